// Round 14
// baseline (118.235 us; speedup 1.0000x reference)
//
#include <hip/hip_runtime.h>

#define NB 4
#define NN 4096
#define NT 16
#define NC 64
#define NE 32768
#define XR 72    // LDS tile row stride (bf16 elems); 144B = 16B-aligned, bank-spread
#define MPB 2    // nodes per block (GLU kernels)

typedef unsigned int uint;
typedef unsigned char uchar;
typedef unsigned short ushort;

typedef short bf16x8 __attribute__((ext_vector_type(8)));
typedef float f32x4 __attribute__((ext_vector_type(4)));

union ABu { uint2 u2[2]; bf16x8 v; };

__device__ inline ushort f2b(float f) {
  union { float f; uint u; } v; v.f = f;
  uint r = v.u + 0x7FFF + ((v.u >> 16) & 1);
  return (ushort)(r >> 16);
}
__device__ inline float blo(uint u) { union { uint i; float f; } v; v.i = u << 16; return v.f; }
__device__ inline float bhi(uint u) { union { uint i; float f; } v; v.i = u & 0xffff0000u; return v.f; }
// fp8 e4m3 via HW converts (pack+unpack same HW -> self-consistent; absmax unchanged R9->R13)
__device__ inline uchar f2fp8(float f) {
  int w = __builtin_amdgcn_cvt_pk_fp8_f32(f, f, 0, false);
  return (uchar)(w & 0xff);
}
// byte-select of cvt_f32_fp8 must be a LITERAL (R12 compile lesson) — expand all 4
__device__ inline void fp8x4(uint u, float* o) {
  o[0] = __builtin_amdgcn_cvt_f32_fp8(u, 0);
  o[1] = __builtin_amdgcn_cvt_f32_fp8(u, 1);
  o[2] = __builtin_amdgcn_cvt_f32_fp8(u, 2);
  o[3] = __builtin_amdgcn_cvt_f32_fp8(u, 3);
}

// ---------------- prep: weight packing + count zeroing ----------------
__global__ void k_prep(const float* __restrict__ W1, const float* __restrict__ W2,
                       const float* __restrict__ Wg,
                       ushort* __restrict__ Bp1, ushort* __restrict__ Bp2,
                       ushort* __restrict__ Wgp, int* __restrict__ count) {
  int i = blockIdx.x * blockDim.x + threadIdx.x;
  if (i < 24576) {
    int j = i & 7, l = (i >> 3) & 63, nt = (i >> 9) & 7, s = i >> 12;
    int kap = 32 * s + 4 * (l >> 4) + (j & 3) + 16 * (j >> 2);
    int c = kap & 63, kk = kap >> 6, o = nt * 16 + (l & 15);
    Bp1[i] = f2b(W1[o * 192 + c * 3 + kk]);
    Bp2[i] = f2b(W2[o * 192 + c * 3 + kk]);
  } else if (i < 28672) {
    int i2 = i - 24576;
    int j = i2 & 7, l = (i2 >> 3) & 63, nt2 = (i2 >> 9) & 3, s2 = i2 >> 11;
    int kap = 32 * s2 + 4 * (l >> 4) + (j & 3) + 16 * (j >> 2);
    int d = nt2 * 16 + (l & 15);
    Wgp[i2] = f2b(Wg[d * 64 + kap]);
  } else {
    count[i - 28672] = 0;
  }
}

// CSR build: parallel kernels (R10 lesson: 1-block merged CSR serialized the dispatch)
__global__ void k_count(const int* __restrict__ src, int* __restrict__ count) {
  int e = blockIdx.x * blockDim.x + threadIdx.x;
  if (e < NE) atomicAdd(&count[src[e]], 1);
}

__global__ void k_scan(const int* __restrict__ count, int* __restrict__ offsets,
                       int* __restrict__ cursor) {
  __shared__ int part[256];
  int tid = threadIdx.x;
  int base = tid * 16;
  int s = 0;
  for (int i = 0; i < 16; ++i) s += count[base + i];
  part[tid] = s;
  __syncthreads();
  if (tid == 0) {
    int r = 0;
    for (int i = 0; i < 256; ++i) { int t = part[i]; part[i] = r; r += t; }
    offsets[NN] = r;
  }
  __syncthreads();
  int r = part[tid];
  for (int i = 0; i < 16; ++i) {
    offsets[base + i] = r;
    cursor[base + i] = r;
    r += count[base + i];
  }
}

__global__ void k_place(const int* __restrict__ src, const int* __restrict__ dst,
                        const float* __restrict__ ew, int* __restrict__ cursor,
                        int* __restrict__ dsts, float* __restrict__ wsrt) {
  int e = blockIdx.x * blockDim.x + threadIdx.x;
  if (e < NE) {
    int p = atomicAdd(&cursor[src[e]], 1);
    dsts[p] = dst[e];
    wsrt[p] = ew[e];
  }
}

// ---------------- GLU1(MFMA) + GCN-linear(MFMA): 2 nodes/block, 4 waves ----------------
// (256,4): unified-file check 44 VGPR + 48 AGPR = 92 <= 128-cap (R5 lesson: verify no spill via FETCH)
__global__ __launch_bounds__(256, 4) void k_glu1lin(
    const float* __restrict__ x, const ushort* __restrict__ Bp1,
    const float* __restrict__ b1, const ushort* __restrict__ Wgp,
    const float* __restrict__ bg, uchar* __restrict__ y) {
  __shared__ ushort As[MPB * 4 * 18 * XR + 64 * 68];  // tiles + hs; 29440 B
  ushort* hs = As + MPB * 4 * 18 * XR;
  int tid = threadIdx.x;
  int n0 = blockIdx.x * MPB;
  int w = tid >> 6, l = tid & 63, m = l & 15, g4 = l >> 4;

  bf16x8 bc[6][2];
  #pragma unroll
  for (int s = 0; s < 6; ++s) {
    bc[s][0] = *(const bf16x8*)&Bp1[((s * 8 + w) * 64 + l) * 8];
    bc[s][1] = *(const bf16x8*)&Bp1[((s * 8 + w + 4) * 64 + l) * 8];
  }
  bf16x8 wg2[2];
  #pragma unroll
  for (int s2 = 0; s2 < 2; ++s2)
    wg2[s2] = *(const bf16x8*)&Wgp[((s2 * 4 + w) * 64 + l) * 8];

  {
    int nd = tid >> 7, rem = tid & 127;
    int b = rem >> 5, tp = ((rem >> 4) & 1) ? 17 : 0, c4 = (rem & 15) * 4;
    *(uint2*)&As[((nd * 4 + b) * 18 + tp) * XR + c4] = make_uint2(0, 0);
  }
  const float4* x4 = (const float4*)x;
  #pragma unroll
  for (int q = 0; q < 8; ++q) {
    int f4 = q * 256 + tid;
    int nd = f4 >> 10, rem = f4 & 1023;
    int b = rem >> 8, r = rem & 255, tau = r >> 4, c4i = r & 15;
    float4 v = x4[((b * NN + n0 + nd) * 16 + tau) * 16 + c4i];
    uint2 p;
    p.x = (uint)f2b(v.x) | ((uint)f2b(v.y) << 16);
    p.y = (uint)f2b(v.z) | ((uint)f2b(v.w) << 16);
    *(uint2*)&As[((nd * 4 + b) * 18 + tau + 1) * XR + c4i * 4] = p;
  }
  __syncthreads();

  float bv = b1[w * 16 + m], bgate = b1[64 + w * 16 + m];
  float bgl = bg[w * 16 + m];

  #pragma unroll
  for (int nd = 0; nd < MPB; ++nd) {
    int nd4 = nd * 4;
    f32x4 acc[4][2];
    #pragma unroll
    for (int rt = 0; rt < 4; ++rt) {
      acc[rt][0] = (f32x4){bv, bv, bv, bv};
      acc[rt][1] = (f32x4){bgate, bgate, bgate, bgate};
    }
    #pragma unroll
    for (int s = 0; s < 6; ++s) {
      const int kk = s >> 1, sp = s & 1;
      int col = 32 * sp + 4 * g4;
      #pragma unroll
      for (int rt = 0; rt < 4; ++rt) {
        int r0 = ((nd4 + rt) * 18 + m + kk) * XR + col;
        ABu a;
        a.u2[0] = *(const uint2*)&As[r0];
        a.u2[1] = *(const uint2*)&As[r0 + 16];
        acc[rt][0] = __builtin_amdgcn_mfma_f32_16x16x32_bf16(a.v, bc[s][0], acc[rt][0], 0, 0, 0);
        acc[rt][1] = __builtin_amdgcn_mfma_f32_16x16x32_bf16(a.v, bc[s][1], acc[rt][1], 0, 0, 0);
      }
    }
    #pragma unroll
    for (int rt = 0; rt < 4; ++rt)
      #pragma unroll
      for (int i = 0; i < 4; ++i) {
        float v = acc[rt][0][i], gt = acc[rt][1][i];
        float h = fmaxf(v / (1.f + __expf(-gt)), 0.f);
        hs[(rt * 16 + 4 * g4 + i) * 68 + w * 16 + m] = f2b(h);
      }
    __syncthreads();

    f32x4 acc2[4];
    #pragma unroll
    for (int rt = 0; rt < 4; ++rt) acc2[rt] = (f32x4){bgl, bgl, bgl, bgl};
    #pragma unroll
    for (int s2 = 0; s2 < 2; ++s2) {
      #pragma unroll
      for (int rt = 0; rt < 4; ++rt) {
        int rb = (rt * 16 + m) * 68 + 32 * s2 + 4 * g4;
        ABu a;
        a.u2[0] = *(const uint2*)&hs[rb];
        a.u2[1] = *(const uint2*)&hs[rb + 16];
        acc2[rt] = __builtin_amdgcn_mfma_f32_16x16x32_bf16(a.v, wg2[s2], acc2[rt], 0, 0, 0);
      }
    }
    uchar* yb = y + ((size_t)(n0 + nd) * NB) * 1024;
    #pragma unroll
    for (int rt = 0; rt < 4; ++rt)
      #pragma unroll
      for (int i = 0; i < 4; ++i) {
        int t = 4 * g4 + i;
        yb[rt * 1024 + t * 64 + w * 16 + m] = f2fp8(acc2[rt][i]);
      }
    __syncthreads();
  }
}

// ---------------- GCN-gather(fp8) + GLU2(MFMA) + residual + stats, fused ----------------
// Gather: thread owns 16 consecutive fp8 elems of each node's 4096-vector; edge loads
// are independent coalesced 16B/lane, unroll x4 (R13: deeper in-flight for L3 latency).
// (256,4): 68 VGPR + 32 AGPR + ~12 pipeline = ~112 <= 128-cap.
__global__ __launch_bounds__(256, 4) void k_glu2(
    const uchar* __restrict__ y8, const float* __restrict__ x,
    const ushort* __restrict__ Bp2, const float* __restrict__ b2,
    const int* __restrict__ offsets, const int* __restrict__ dsts,
    const float* __restrict__ wsrt,
    ushort* __restrict__ outb, float* __restrict__ partials) {
  __shared__ ushort As[MPB * 4 * 18 * XR];   // 20736 B
  __shared__ float red[512];
  int tid = threadIdx.x;
  int n0 = blockIdx.x * MPB;
  int w = tid >> 6, l = tid & 63, m = l & 15, g4 = l >> 4;

  bf16x8 bc[6][2];
  #pragma unroll
  for (int s = 0; s < 6; ++s) {
    bc[s][0] = *(const bf16x8*)&Bp2[((s * 8 + w) * 64 + l) * 8];
    bc[s][1] = *(const bf16x8*)&Bp2[((s * 8 + w + 4) * 64 + l) * 8];
  }

  {
    int nd = tid >> 7, rem = tid & 127;
    int b = rem >> 5, tp = ((rem >> 4) & 1) ? 17 : 0, c4 = (rem & 15) * 4;
    *(uint2*)&As[((nd * 4 + b) * 18 + tp) * XR + c4] = make_uint2(0, 0);
  }

  // gather: thread covers node elems [tid*16, tid*16+16): b=tid>>6, t=(tid>>2)&15, c0=(tid&3)*16
  #pragma unroll
  for (int nd = 0; nd < MPB; ++nd) {
    int n = n0 + nd;
    int e0 = offsets[n], e1 = offsets[n + 1];
    float ga[16];
    #pragma unroll
    for (int j = 0; j < 16; ++j) ga[j] = 0.f;
    const uchar* ybase = y8 + tid * 16;
    int e = e0;
    for (; e + 4 <= e1; e += 4) {
      uint4 v[4];
      float wt[4];
      #pragma unroll
      for (int u = 0; u < 4; ++u) {
        int d = dsts[e + u];
        wt[u] = wsrt[e + u];
        v[u] = *(const uint4*)(ybase + (size_t)d * 4096);
      }
      #pragma unroll
      for (int u = 0; u < 4; ++u) {
        float f[16];
        fp8x4(v[u].x, f); fp8x4(v[u].y, f + 4); fp8x4(v[u].z, f + 8); fp8x4(v[u].w, f + 12);
        #pragma unroll
        for (int j = 0; j < 16; ++j) ga[j] += wt[u] * f[j];
      }
    }
    for (; e < e1; ++e) {
      int d0 = dsts[e];
      float w0 = wsrt[e];
      uint4 v0 = *(const uint4*)(ybase + (size_t)d0 * 4096);
      float f0[16];
      fp8x4(v0.x, f0); fp8x4(v0.y, f0 + 4); fp8x4(v0.z, f0 + 8); fp8x4(v0.w, f0 + 12);
      #pragma unroll
      for (int j = 0; j < 16; ++j)
        ga[j] += w0 * f0[j];
    }
    // ReLU + pack -> conv tile (32B contiguous per thread)
    int b = tid >> 6, t = (tid >> 2) & 15, c0 = (tid & 3) * 16;
    uint pk[8];
    #pragma unroll
    for (int j = 0; j < 8; ++j)
      pk[j] = (uint)f2b(fmaxf(ga[2 * j], 0.f)) | ((uint)f2b(fmaxf(ga[2 * j + 1], 0.f)) << 16);
    ushort* dstp = &As[((nd * 4 + b) * 18 + t + 1) * XR + c0];
    *(uint4*)dstp = make_uint4(pk[0], pk[1], pk[2], pk[3]);
    *(uint4*)(dstp + 8) = make_uint4(pk[4], pk[5], pk[6], pk[7]);
  }
  __syncthreads();

  float bv = b2[w * 16 + m], bgate = b2[64 + w * 16 + m];
  float p1 = 0.f, p2 = 0.f;

  #pragma unroll
  for (int nd = 0; nd < MPB; ++nd) {
    int n = n0 + nd, nd4 = nd * 4;
    // residual loads issued at conv start: in flight under the conv
    float xr[4][4];
    #pragma unroll
    for (int rt = 0; rt < 4; ++rt) {
      const float* xb = x + ((size_t)rt * NN + n) * 1024 + w * 16 + m;
      #pragma unroll
      for (int i = 0; i < 4; ++i)
        xr[rt][i] = xb[(4 * g4 + i) * 64];
    }
    f32x4 acc[4][2];
    #pragma unroll
    for (int rt = 0; rt < 4; ++rt) {
      acc[rt][0] = (f32x4){bv, bv, bv, bv};
      acc[rt][1] = (f32x4){bgate, bgate, bgate, bgate};
    }
    #pragma unroll
    for (int s = 0; s < 6; ++s) {
      const int kk = s >> 1, sp = s & 1;
      int col = 32 * sp + 4 * g4;
      #pragma unroll
      for (int rt = 0; rt < 4; ++rt) {
        int r0 = ((nd4 + rt) * 18 + m + kk) * XR + col;
        ABu a;
        a.u2[0] = *(const uint2*)&As[r0];
        a.u2[1] = *(const uint2*)&As[r0 + 16];
        acc[rt][0] = __builtin_amdgcn_mfma_f32_16x16x32_bf16(a.v, bc[s][0], acc[rt][0], 0, 0, 0);
        acc[rt][1] = __builtin_amdgcn_mfma_f32_16x16x32_bf16(a.v, bc[s][1], acc[rt][1], 0, 0, 0);
      }
    }
    #pragma unroll
    for (int rt = 0; rt < 4; ++rt)
      #pragma unroll
      for (int i = 0; i < 4; ++i) {
        float v = acc[rt][0][i], gt = acc[rt][1][i];
        float h = v / (1.f + __expf(-gt));
        int t = 4 * g4 + i;
        float res = h + xr[rt][i];
        outb[((rt * NN + n) * 16 + t) * 64 + w * 16 + m] = f2b(res);
        p1 += res;
        p2 += res * res;
      }
  }
  red[(w * 16 + m) * 4 + g4] = p1;
  red[256 + (w * 16 + m) * 4 + g4] = p2;
  __syncthreads();
  if (tid < 64) {
    float s = red[tid * 4] + red[tid * 4 + 1] + red[tid * 4 + 2] + red[tid * 4 + 3];
    partials[tid * (NN / MPB) + blockIdx.x] = s;
  } else if (tid < 128) {
    int c = tid - 64;
    float s = red[256 + c * 4] + red[256 + c * 4 + 1] + red[256 + c * 4 + 2] + red[256 + c * 4 + 3];
    partials[(64 + c) * (NN / MPB) + blockIdx.x] = s;
  }
}

// ---------------- reduce partials -> chan[128] ----------------
__global__ __launch_bounds__(256) void k_reduce(const float* __restrict__ partials,
                                                float* __restrict__ chan) {
  __shared__ float sm[256];
  int r = blockIdx.x, tid = threadIdx.x;
  const float* p = partials + (size_t)r * (NN / MPB);
  float s = 0.f;
  for (int i = tid; i < NN / MPB; i += 256) s += p[i];
  sm[tid] = s;
  __syncthreads();
  for (int w = 128; w >= 1; w >>= 1) {
    if (tid < w) sm[tid] += sm[tid + w];
    __syncthreads();
  }
  if (tid == 0) chan[r] = sm[0];
}

// ---------------- layernorm + relu: bf16 in -> f32 out ----------------
__global__ __launch_bounds__(256) void k_norm(
    const ushort* __restrict__ outb, float* __restrict__ out,
    const float* __restrict__ chan, const float* __restrict__ gamma,
    const float* __restrict__ beta) {
  __shared__ float sc[64], sh[64];
  int tid = threadIdx.x;
  if (tid < 64) {
    const float inv = 1.f / (float)(NB * NN * NT);
    float mean = chan[tid] * inv;
    float var = chan[64 + tid] * inv - mean * mean;
    float s = rsqrtf(var + 1e-5f) * gamma[tid];
    sc[tid] = s;
    sh[tid] = beta[tid] - mean * s;
  }
  __syncthreads();
  const uint4* i4 = (const uint4*)outb;
  const int total = NB * NN * NT * 8;   // uint4 count (8 bf16 each)
  for (int i = blockIdx.x * blockDim.x + threadIdx.x; i < total;
       i += gridDim.x * blockDim.x) {
    uint4 v = i4[i];
    int c0 = (i & 7) * 8;
    float4 o0, o1;
    o0.x = fmaxf(blo(v.x) * sc[c0 + 0] + sh[c0 + 0], 0.f);
    o0.y = fmaxf(bhi(v.x) * sc[c0 + 1] + sh[c0 + 1], 0.f);
    o0.z = fmaxf(blo(v.y) * sc[c0 + 2] + sh[c0 + 2], 0.f);
    o0.w = fmaxf(bhi(v.y) * sc[c0 + 3] + sh[c0 + 3], 0.f);
    o1.x = fmaxf(blo(v.z) * sc[c0 + 4] + sh[c0 + 4], 0.f);
    o1.y = fmaxf(bhi(v.z) * sc[c0 + 5] + sh[c0 + 5], 0.f);
    o1.z = fmaxf(blo(v.w) * sc[c0 + 6] + sh[c0 + 6], 0.f);
    o1.w = fmaxf(bhi(v.w) * sc[c0 + 7] + sh[c0 + 7], 0.f);
    ((float4*)out)[i * 2] = o0;
    ((float4*)out)[i * 2 + 1] = o1;
  }
}

// ---------------- launch ----------------

extern "C" void kernel_launch(void* const* d_in, const int* in_sizes, int n_in,
                              void* d_out, int out_size, void* d_ws, size_t ws_size,
                              hipStream_t stream) {
  const float* x    = (const float*)d_in[0];
  const int* esrc   = (const int*)d_in[1];
  const int* edst   = (const int*)d_in[2];
  const float* ew   = (const float*)d_in[3];
  const float* W1   = (const float*)d_in[4];
  const float* b1   = (const float*)d_in[5];
  const float* Wg   = (const float*)d_in[6];
  const float* bg   = (const float*)d_in[7];
  const float* W2   = (const float*)d_in[8];
  const float* b2   = (const float*)d_in[9];
  const float* gamma = (const float*)d_in[10];
  const float* beta  = (const float*)d_in[11];
  float* out = (float*)d_out;

  uchar* y8      = (uchar*)d_ws;              // 16777216 fp8 bytes (node-major)
  ushort* outb   = (ushort*)(y8 + 16777216);  // 16777216 bf16 (pre-norm out)
  ushort* Bp1    = outb + 16777216;           // 24576
  ushort* Bp2    = Bp1 + 24576;               // 24576
  ushort* Wgp    = Bp2 + 24576;               // 4096
  float* chan    = (float*)(Wgp + 4096);      // 128
  int* count   = (int*)(chan + 128);          // 4096
  int* offsets = count + 4096;                // 4097
  int* cursor  = offsets + 4097;              // 4096
  int* dsts    = cursor + 4096;               // 32768 (pre-sorted edge dst)
  float* wsrt  = (float*)(dsts + NE);         // 32768 (pre-sorted edge weight)
  float* partials = wsrt + NE;                // 128*(NN/MPB) = 262144 floats

  hipLaunchKernelGGL(k_prep, dim3(128), dim3(256), 0, stream, W1, W2, Wg, Bp1, Bp2, Wgp, count);
  hipLaunchKernelGGL(k_count, dim3(128), dim3(256), 0, stream, esrc, count);
  hipLaunchKernelGGL(k_scan, dim3(1), dim3(256), 0, stream, count, offsets, cursor);
  hipLaunchKernelGGL(k_place, dim3(128), dim3(256), 0, stream, esrc, edst, ew, cursor, dsts, wsrt);
  hipLaunchKernelGGL(k_glu1lin, dim3(NN / MPB), dim3(256), 0, stream,
                     x, Bp1, b1, Wgp, bg, y8);
  hipLaunchKernelGGL(k_glu2, dim3(NN / MPB), dim3(256), 0, stream,
                     y8, x, Bp2, b2, offsets, dsts, wsrt, outb, partials);
  hipLaunchKernelGGL(k_reduce, dim3(128), dim3(256), 0, stream, partials, chan);
  hipLaunchKernelGGL(k_norm, dim3(2048), dim3(256), 0, stream,
                     outb, out, chan, gamma, beta);
}

// Round 15
// 108.425 us; speedup vs baseline: 1.0905x; 1.0905x over previous
//
#include <hip/hip_runtime.h>

#define NB 4
#define NN 4096
#define NT 16
#define NC 64
#define NE 32768
#define XR 72    // LDS tile row stride (bf16 elems); 144B = 16B-aligned, bank-spread
#define MPB 2    // nodes per block (GLU kernels)

typedef unsigned int uint;
typedef unsigned char uchar;
typedef unsigned short ushort;

typedef short bf16x8 __attribute__((ext_vector_type(8)));
typedef float f32x4 __attribute__((ext_vector_type(4)));

union ABu { uint2 u2[2]; bf16x8 v; };

__device__ inline ushort f2b(float f) {
  union { float f; uint u; } v; v.f = f;
  uint r = v.u + 0x7FFF + ((v.u >> 16) & 1);
  return (ushort)(r >> 16);
}
__device__ inline float blo(uint u) { union { uint i; float f; } v; v.i = u << 16; return v.f; }
__device__ inline float bhi(uint u) { union { uint i; float f; } v; v.i = u & 0xffff0000u; return v.f; }
// fp8 e4m3 via HW converts (pack+unpack same HW -> self-consistent; absmax unchanged R9->R13)
__device__ inline uchar f2fp8(float f) {
  int w = __builtin_amdgcn_cvt_pk_fp8_f32(f, f, 0, false);
  return (uchar)(w & 0xff);
}
// byte-select of cvt_f32_fp8 must be a LITERAL (R12 compile lesson) — expand all 4
__device__ inline void fp8x4(uint u, float* o) {
  o[0] = __builtin_amdgcn_cvt_f32_fp8(u, 0);
  o[1] = __builtin_amdgcn_cvt_f32_fp8(u, 1);
  o[2] = __builtin_amdgcn_cvt_f32_fp8(u, 2);
  o[3] = __builtin_amdgcn_cvt_f32_fp8(u, 3);
}

// ---------------- prep: weight packing + count zeroing ----------------
__global__ void k_prep(const float* __restrict__ W1, const float* __restrict__ W2,
                       const float* __restrict__ Wg,
                       ushort* __restrict__ Bp1, ushort* __restrict__ Bp2,
                       ushort* __restrict__ Wgp, int* __restrict__ count) {
  int i = blockIdx.x * blockDim.x + threadIdx.x;
  if (i < 24576) {
    int j = i & 7, l = (i >> 3) & 63, nt = (i >> 9) & 7, s = i >> 12;
    int kap = 32 * s + 4 * (l >> 4) + (j & 3) + 16 * (j >> 2);
    int c = kap & 63, kk = kap >> 6, o = nt * 16 + (l & 15);
    Bp1[i] = f2b(W1[o * 192 + c * 3 + kk]);
    Bp2[i] = f2b(W2[o * 192 + c * 3 + kk]);
  } else if (i < 28672) {
    int i2 = i - 24576;
    int j = i2 & 7, l = (i2 >> 3) & 63, nt2 = (i2 >> 9) & 3, s2 = i2 >> 11;
    int kap = 32 * s2 + 4 * (l >> 4) + (j & 3) + 16 * (j >> 2);
    int d = nt2 * 16 + (l & 15);
    Wgp[i2] = f2b(Wg[d * 64 + kap]);
  } else {
    count[i - 28672] = 0;
  }
}

// CSR build: parallel kernels (R10 lesson: 1-block merged CSR serialized the dispatch)
__global__ void k_count(const int* __restrict__ src, int* __restrict__ count) {
  int e = blockIdx.x * blockDim.x + threadIdx.x;
  if (e < NE) atomicAdd(&count[src[e]], 1);
}

__global__ void k_scan(const int* __restrict__ count, int* __restrict__ offsets,
                       int* __restrict__ cursor) {
  __shared__ int part[256];
  int tid = threadIdx.x;
  int base = tid * 16;
  int s = 0;
  for (int i = 0; i < 16; ++i) s += count[base + i];
  part[tid] = s;
  __syncthreads();
  if (tid == 0) {
    int r = 0;
    for (int i = 0; i < 256; ++i) { int t = part[i]; part[i] = r; r += t; }
    offsets[NN] = r;
  }
  __syncthreads();
  int r = part[tid];
  for (int i = 0; i < 16; ++i) {
    offsets[base + i] = r;
    cursor[base + i] = r;
    r += count[base + i];
  }
}

__global__ void k_place(const int* __restrict__ src, const int* __restrict__ dst,
                        const float* __restrict__ ew, int* __restrict__ cursor,
                        int* __restrict__ dsts, float* __restrict__ wsrt) {
  int e = blockIdx.x * blockDim.x + threadIdx.x;
  if (e < NE) {
    int p = atomicAdd(&cursor[src[e]], 1);
    dsts[p] = dst[e];
    wsrt[p] = ew[e];
  }
}

// ---------------- GLU1(MFMA) + GCN-linear(MFMA): 2 nodes/block, 4 waves ----------------
// (256,3): R14 lesson — (256,4) squeezed VGPR to 64 and spilled the pipeline temps
// (WRITE_SIZE 42->71MB scratch). 3-wave cap (~170) is the proven config.
__global__ __launch_bounds__(256, 3) void k_glu1lin(
    const float* __restrict__ x, const ushort* __restrict__ Bp1,
    const float* __restrict__ b1, const ushort* __restrict__ Wgp,
    const float* __restrict__ bg, uchar* __restrict__ y) {
  __shared__ ushort As[MPB * 4 * 18 * XR + 64 * 68];  // tiles + hs; 29440 B
  ushort* hs = As + MPB * 4 * 18 * XR;
  int tid = threadIdx.x;
  int n0 = blockIdx.x * MPB;
  int w = tid >> 6, l = tid & 63, m = l & 15, g4 = l >> 4;

  bf16x8 bc[6][2];
  #pragma unroll
  for (int s = 0; s < 6; ++s) {
    bc[s][0] = *(const bf16x8*)&Bp1[((s * 8 + w) * 64 + l) * 8];
    bc[s][1] = *(const bf16x8*)&Bp1[((s * 8 + w + 4) * 64 + l) * 8];
  }
  bf16x8 wg2[2];
  #pragma unroll
  for (int s2 = 0; s2 < 2; ++s2)
    wg2[s2] = *(const bf16x8*)&Wgp[((s2 * 4 + w) * 64 + l) * 8];

  {
    int nd = tid >> 7, rem = tid & 127;
    int b = rem >> 5, tp = ((rem >> 4) & 1) ? 17 : 0, c4 = (rem & 15) * 4;
    *(uint2*)&As[((nd * 4 + b) * 18 + tp) * XR + c4] = make_uint2(0, 0);
  }
  const float4* x4 = (const float4*)x;
  #pragma unroll
  for (int q = 0; q < 8; ++q) {
    int f4 = q * 256 + tid;
    int nd = f4 >> 10, rem = f4 & 1023;
    int b = rem >> 8, r = rem & 255, tau = r >> 4, c4i = r & 15;
    float4 v = x4[((b * NN + n0 + nd) * 16 + tau) * 16 + c4i];
    uint2 p;
    p.x = (uint)f2b(v.x) | ((uint)f2b(v.y) << 16);
    p.y = (uint)f2b(v.z) | ((uint)f2b(v.w) << 16);
    *(uint2*)&As[((nd * 4 + b) * 18 + tau + 1) * XR + c4i * 4] = p;
  }
  __syncthreads();

  float bv = b1[w * 16 + m], bgate = b1[64 + w * 16 + m];
  float bgl = bg[w * 16 + m];

  #pragma unroll
  for (int nd = 0; nd < MPB; ++nd) {
    int nd4 = nd * 4;
    f32x4 acc[4][2];
    #pragma unroll
    for (int rt = 0; rt < 4; ++rt) {
      acc[rt][0] = (f32x4){bv, bv, bv, bv};
      acc[rt][1] = (f32x4){bgate, bgate, bgate, bgate};
    }
    #pragma unroll
    for (int s = 0; s < 6; ++s) {
      const int kk = s >> 1, sp = s & 1;
      int col = 32 * sp + 4 * g4;
      #pragma unroll
      for (int rt = 0; rt < 4; ++rt) {
        int r0 = ((nd4 + rt) * 18 + m + kk) * XR + col;
        ABu a;
        a.u2[0] = *(const uint2*)&As[r0];
        a.u2[1] = *(const uint2*)&As[r0 + 16];
        acc[rt][0] = __builtin_amdgcn_mfma_f32_16x16x32_bf16(a.v, bc[s][0], acc[rt][0], 0, 0, 0);
        acc[rt][1] = __builtin_amdgcn_mfma_f32_16x16x32_bf16(a.v, bc[s][1], acc[rt][1], 0, 0, 0);
      }
    }
    #pragma unroll
    for (int rt = 0; rt < 4; ++rt)
      #pragma unroll
      for (int i = 0; i < 4; ++i) {
        float v = acc[rt][0][i], gt = acc[rt][1][i];
        float h = fmaxf(v / (1.f + __expf(-gt)), 0.f);
        hs[(rt * 16 + 4 * g4 + i) * 68 + w * 16 + m] = f2b(h);
      }
    __syncthreads();

    f32x4 acc2[4];
    #pragma unroll
    for (int rt = 0; rt < 4; ++rt) acc2[rt] = (f32x4){bgl, bgl, bgl, bgl};
    #pragma unroll
    for (int s2 = 0; s2 < 2; ++s2) {
      #pragma unroll
      for (int rt = 0; rt < 4; ++rt) {
        int rb = (rt * 16 + m) * 68 + 32 * s2 + 4 * g4;
        ABu a;
        a.u2[0] = *(const uint2*)&hs[rb];
        a.u2[1] = *(const uint2*)&hs[rb + 16];
        acc2[rt] = __builtin_amdgcn_mfma_f32_16x16x32_bf16(a.v, wg2[s2], acc2[rt], 0, 0, 0);
      }
    }
    uchar* yb = y + ((size_t)(n0 + nd) * NB) * 1024;
    #pragma unroll
    for (int rt = 0; rt < 4; ++rt)
      #pragma unroll
      for (int i = 0; i < 4; ++i) {
        int t = 4 * g4 + i;
        yb[rt * 1024 + t * 64 + w * 16 + m] = f2fp8(acc2[rt][i]);
      }
    __syncthreads();
  }
}

// ---------------- GCN-gather(fp8) + GLU2(MFMA) + residual + stats, fused ----------------
// Gather: thread owns 16 consecutive fp8 elems of each node's 4096-vector; edge loads
// are independent coalesced 16B/lane, unroll x4. (256,3) — see R14 spill lesson above.
__global__ __launch_bounds__(256, 3) void k_glu2(
    const uchar* __restrict__ y8, const float* __restrict__ x,
    const ushort* __restrict__ Bp2, const float* __restrict__ b2,
    const int* __restrict__ offsets, const int* __restrict__ dsts,
    const float* __restrict__ wsrt,
    ushort* __restrict__ outb, float* __restrict__ partials) {
  __shared__ ushort As[MPB * 4 * 18 * XR];   // 20736 B
  __shared__ float red[512];
  int tid = threadIdx.x;
  int n0 = blockIdx.x * MPB;
  int w = tid >> 6, l = tid & 63, m = l & 15, g4 = l >> 4;

  bf16x8 bc[6][2];
  #pragma unroll
  for (int s = 0; s < 6; ++s) {
    bc[s][0] = *(const bf16x8*)&Bp2[((s * 8 + w) * 64 + l) * 8];
    bc[s][1] = *(const bf16x8*)&Bp2[((s * 8 + w + 4) * 64 + l) * 8];
  }

  {
    int nd = tid >> 7, rem = tid & 127;
    int b = rem >> 5, tp = ((rem >> 4) & 1) ? 17 : 0, c4 = (rem & 15) * 4;
    *(uint2*)&As[((nd * 4 + b) * 18 + tp) * XR + c4] = make_uint2(0, 0);
  }

  // gather: thread covers node elems [tid*16, tid*16+16): b=tid>>6, t=(tid>>2)&15, c0=(tid&3)*16
  #pragma unroll
  for (int nd = 0; nd < MPB; ++nd) {
    int n = n0 + nd;
    int e0 = offsets[n], e1 = offsets[n + 1];
    float ga[16];
    #pragma unroll
    for (int j = 0; j < 16; ++j) ga[j] = 0.f;
    const uchar* ybase = y8 + tid * 16;
    int e = e0;
    for (; e + 4 <= e1; e += 4) {
      uint4 v[4];
      float wt[4];
      #pragma unroll
      for (int u = 0; u < 4; ++u) {
        int d = dsts[e + u];
        wt[u] = wsrt[e + u];
        v[u] = *(const uint4*)(ybase + (size_t)d * 4096);
      }
      #pragma unroll
      for (int u = 0; u < 4; ++u) {
        float f[16];
        fp8x4(v[u].x, f); fp8x4(v[u].y, f + 4); fp8x4(v[u].z, f + 8); fp8x4(v[u].w, f + 12);
        #pragma unroll
        for (int j = 0; j < 16; ++j) ga[j] += wt[u] * f[j];
      }
    }
    for (; e < e1; ++e) {
      int d0 = dsts[e];
      float w0 = wsrt[e];
      uint4 v0 = *(const uint4*)(ybase + (size_t)d0 * 4096);
      float f0[16];
      fp8x4(v0.x, f0); fp8x4(v0.y, f0 + 4); fp8x4(v0.z, f0 + 8); fp8x4(v0.w, f0 + 12);
      #pragma unroll
      for (int j = 0; j < 16; ++j)
        ga[j] += w0 * f0[j];
    }
    // ReLU + pack -> conv tile (32B contiguous per thread)
    int b = tid >> 6, t = (tid >> 2) & 15, c0 = (tid & 3) * 16;
    uint pk[8];
    #pragma unroll
    for (int j = 0; j < 8; ++j)
      pk[j] = (uint)f2b(fmaxf(ga[2 * j], 0.f)) | ((uint)f2b(fmaxf(ga[2 * j + 1], 0.f)) << 16);
    ushort* dstp = &As[((nd * 4 + b) * 18 + t + 1) * XR + c0];
    *(uint4*)dstp = make_uint4(pk[0], pk[1], pk[2], pk[3]);
    *(uint4*)(dstp + 8) = make_uint4(pk[4], pk[5], pk[6], pk[7]);
  }
  __syncthreads();

  float bv = b2[w * 16 + m], bgate = b2[64 + w * 16 + m];
  float p1 = 0.f, p2 = 0.f;

  #pragma unroll
  for (int nd = 0; nd < MPB; ++nd) {
    int n = n0 + nd, nd4 = nd * 4;
    // residual loads issued at conv start: in flight under the conv
    float xr[4][4];
    #pragma unroll
    for (int rt = 0; rt < 4; ++rt) {
      const float* xb = x + ((size_t)rt * NN + n) * 1024 + w * 16 + m;
      #pragma unroll
      for (int i = 0; i < 4; ++i)
        xr[rt][i] = xb[(4 * g4 + i) * 64];
    }
    f32x4 acc[4][2];
    #pragma unroll
    for (int rt = 0; rt < 4; ++rt) {
      acc[rt][0] = (f32x4){bv, bv, bv, bv};
      acc[rt][1] = (f32x4){bgate, bgate, bgate, bgate};
    }
    #pragma unroll
    for (int s = 0; s < 6; ++s) {
      const int kk = s >> 1, sp = s & 1;
      int col = 32 * sp + 4 * g4;
      #pragma unroll
      for (int rt = 0; rt < 4; ++rt) {
        int r0 = ((nd4 + rt) * 18 + m + kk) * XR + col;
        ABu a;
        a.u2[0] = *(const uint2*)&As[r0];
        a.u2[1] = *(const uint2*)&As[r0 + 16];
        acc[rt][0] = __builtin_amdgcn_mfma_f32_16x16x32_bf16(a.v, bc[s][0], acc[rt][0], 0, 0, 0);
        acc[rt][1] = __builtin_amdgcn_mfma_f32_16x16x32_bf16(a.v, bc[s][1], acc[rt][1], 0, 0, 0);
      }
    }
    #pragma unroll
    for (int rt = 0; rt < 4; ++rt)
      #pragma unroll
      for (int i = 0; i < 4; ++i) {
        float v = acc[rt][0][i], gt = acc[rt][1][i];
        float h = v / (1.f + __expf(-gt));
        int t = 4 * g4 + i;
        float res = h + xr[rt][i];
        outb[((rt * NN + n) * 16 + t) * 64 + w * 16 + m] = f2b(res);
        p1 += res;
        p2 += res * res;
      }
  }
  red[(w * 16 + m) * 4 + g4] = p1;
  red[256 + (w * 16 + m) * 4 + g4] = p2;
  __syncthreads();
  if (tid < 64) {
    float s = red[tid * 4] + red[tid * 4 + 1] + red[tid * 4 + 2] + red[tid * 4 + 3];
    partials[tid * (NN / MPB) + blockIdx.x] = s;
  } else if (tid < 128) {
    int c = tid - 64;
    float s = red[256 + c * 4] + red[256 + c * 4 + 1] + red[256 + c * 4 + 2] + red[256 + c * 4 + 3];
    partials[(64 + c) * (NN / MPB) + blockIdx.x] = s;
  }
}

// ---------------- reduce partials -> chan[128] ----------------
__global__ __launch_bounds__(256) void k_reduce(const float* __restrict__ partials,
                                                float* __restrict__ chan) {
  __shared__ float sm[256];
  int r = blockIdx.x, tid = threadIdx.x;
  const float* p = partials + (size_t)r * (NN / MPB);
  float s = 0.f;
  for (int i = tid; i < NN / MPB; i += 256) s += p[i];
  sm[tid] = s;
  __syncthreads();
  for (int w = 128; w >= 1; w >>= 1) {
    if (tid < w) sm[tid] += sm[tid + w];
    __syncthreads();
  }
  if (tid == 0) chan[r] = sm[0];
}

// ---------------- layernorm + relu: bf16 in -> f32 out ----------------
__global__ __launch_bounds__(256) void k_norm(
    const ushort* __restrict__ outb, float* __restrict__ out,
    const float* __restrict__ chan, const float* __restrict__ gamma,
    const float* __restrict__ beta) {
  __shared__ float sc[64], sh[64];
  int tid = threadIdx.x;
  if (tid < 64) {
    const float inv = 1.f / (float)(NB * NN * NT);
    float mean = chan[tid] * inv;
    float var = chan[64 + tid] * inv - mean * mean;
    float s = rsqrtf(var + 1e-5f) * gamma[tid];
    sc[tid] = s;
    sh[tid] = beta[tid] - mean * s;
  }
  __syncthreads();
  const uint4* i4 = (const uint4*)outb;
  const int total = NB * NN * NT * 8;   // uint4 count (8 bf16 each)
  for (int i = blockIdx.x * blockDim.x + threadIdx.x; i < total;
       i += gridDim.x * blockDim.x) {
    uint4 v = i4[i];
    int c0 = (i & 7) * 8;
    float4 o0, o1;
    o0.x = fmaxf(blo(v.x) * sc[c0 + 0] + sh[c0 + 0], 0.f);
    o0.y = fmaxf(bhi(v.x) * sc[c0 + 1] + sh[c0 + 1], 0.f);
    o0.z = fmaxf(blo(v.y) * sc[c0 + 2] + sh[c0 + 2], 0.f);
    o0.w = fmaxf(bhi(v.y) * sc[c0 + 3] + sh[c0 + 3], 0.f);
    o1.x = fmaxf(blo(v.z) * sc[c0 + 4] + sh[c0 + 4], 0.f);
    o1.y = fmaxf(bhi(v.z) * sc[c0 + 5] + sh[c0 + 5], 0.f);
    o1.z = fmaxf(blo(v.w) * sc[c0 + 6] + sh[c0 + 6], 0.f);
    o1.w = fmaxf(bhi(v.w) * sc[c0 + 7] + sh[c0 + 7], 0.f);
    ((float4*)out)[i * 2] = o0;
    ((float4*)out)[i * 2 + 1] = o1;
  }
}

// ---------------- launch ----------------

extern "C" void kernel_launch(void* const* d_in, const int* in_sizes, int n_in,
                              void* d_out, int out_size, void* d_ws, size_t ws_size,
                              hipStream_t stream) {
  const float* x    = (const float*)d_in[0];
  const int* esrc   = (const int*)d_in[1];
  const int* edst   = (const int*)d_in[2];
  const float* ew   = (const float*)d_in[3];
  const float* W1   = (const float*)d_in[4];
  const float* b1   = (const float*)d_in[5];
  const float* Wg   = (const float*)d_in[6];
  const float* bg   = (const float*)d_in[7];
  const float* W2   = (const float*)d_in[8];
  const float* b2   = (const float*)d_in[9];
  const float* gamma = (const float*)d_in[10];
  const float* beta  = (const float*)d_in[11];
  float* out = (float*)d_out;

  uchar* y8      = (uchar*)d_ws;              // 16777216 fp8 bytes (node-major)
  ushort* outb   = (ushort*)(y8 + 16777216);  // 16777216 bf16 (pre-norm out)
  ushort* Bp1    = outb + 16777216;           // 24576
  ushort* Bp2    = Bp1 + 24576;               // 24576
  ushort* Wgp    = Bp2 + 24576;               // 4096
  float* chan    = (float*)(Wgp + 4096);      // 128
  int* count   = (int*)(chan + 128);          // 4096
  int* offsets = count + 4096;                // 4097
  int* cursor  = offsets + 4097;              // 4096
  int* dsts    = cursor + 4096;               // 32768 (pre-sorted edge dst)
  float* wsrt  = (float*)(dsts + NE);         // 32768 (pre-sorted edge weight)
  float* partials = wsrt + NE;                // 128*(NN/MPB) = 262144 floats

  hipLaunchKernelGGL(k_prep, dim3(128), dim3(256), 0, stream, W1, W2, Wg, Bp1, Bp2, Wgp, count);
  hipLaunchKernelGGL(k_count, dim3(128), dim3(256), 0, stream, esrc, count);
  hipLaunchKernelGGL(k_scan, dim3(1), dim3(256), 0, stream, count, offsets, cursor);
  hipLaunchKernelGGL(k_place, dim3(128), dim3(256), 0, stream, esrc, edst, ew, cursor, dsts, wsrt);
  hipLaunchKernelGGL(k_glu1lin, dim3(NN / MPB), dim3(256), 0, stream,
                     x, Bp1, b1, Wgp, bg, y8);
  hipLaunchKernelGGL(k_glu2, dim3(NN / MPB), dim3(256), 0, stream,
                     y8, x, Bp2, b2, offsets, dsts, wsrt, outb, partials);
  hipLaunchKernelGGL(k_reduce, dim3(128), dim3(256), 0, stream, partials, chan);
  hipLaunchKernelGGL(k_norm, dim3(2048), dim3(256), 0, stream,
                     outb, out, chan, gamma, beta);
}